// Round 1
// baseline (215.533 us; speedup 1.0000x reference)
//
#include <hip/hip_runtime.h>
#include <math.h>

#define MARGIN 23.0f
#define DIM 256
#define NUM_POS 100000
#define NUM_NEG 100000

#define BLOCK 256
#define WAVES_PER_BLOCK (BLOCK / 64)
#define NBLOCKS 1024

// Stage 1: grid-stride over all 200000 rows (positives then negatives).
// One wave per row per iteration: lane i loads float4 at element 4*i
// (64 lanes x 16B = 1KiB contiguous). Butterfly-sum squared diffs,
// update per-wave running masked-pos-max / neg-min, then block-combine
// into per-block partials in ws.
//
// ws layout (floats): ws[0] = d_pos[0] fallback;
//                     ws[1 .. NBLOCKS]            = per-block pos max (masked)
//                     ws[1+NBLOCKS .. 2*NBLOCKS]  = per-block neg min
__global__ __launch_bounds__(BLOCK) void triplet_stage1(
    const float* __restrict__ anchor,
    const float* __restrict__ pos,
    const float* __restrict__ neg,
    float* __restrict__ ws) {
  __shared__ float s_pos[WAVES_PER_BLOCK];
  __shared__ float s_neg[WAVES_PER_BLOCK];

  const int lane = threadIdx.x & 63;
  const int wid  = threadIdx.x >> 6;

  // Anchor fragment for this lane (broadcast row, cached in regs).
  const float4 av = reinterpret_cast<const float4*>(anchor)[lane];

  float pos_max = -INFINITY;
  float neg_min =  INFINITY;

  const int gwave  = blockIdx.x * WAVES_PER_BLOCK + wid;
  const int nwaves = gridDim.x * WAVES_PER_BLOCK;
  const int total  = NUM_POS + NUM_NEG;

  for (int r = gwave; r < total; r += nwaves) {
    const bool is_pos = (r < NUM_POS);
    const float* row = is_pos ? (pos + (size_t)r * DIM)
                              : (neg + (size_t)(r - NUM_POS) * DIM);
    const float4 pv = reinterpret_cast<const float4*>(row)[lane];

    const float d0 = av.x - pv.x;
    const float d1 = av.y - pv.y;
    const float d2 = av.z - pv.z;
    const float d3 = av.w - pv.w;
    float s = d0 * d0 + d1 * d1 + d2 * d2 + d3 * d3;

    // Butterfly reduce across the 64-lane wave: all lanes get the sum.
    #pragma unroll
    for (int off = 32; off > 0; off >>= 1) {
      s += __shfl_xor(s, off, 64);
    }
    const float d = sqrtf(s);

    if (is_pos) {
      if (r == 0 && lane == 0) ws[0] = d;  // fallback d_pos[0]
      if (d < MARGIN) pos_max = fmaxf(pos_max, d);
    } else {
      neg_min = fminf(neg_min, d);
    }
  }

  if (lane == 0) {
    s_pos[wid] = pos_max;
    s_neg[wid] = neg_min;
  }
  __syncthreads();

  if (threadIdx.x == 0) {
    float pm = s_pos[0];
    float nm = s_neg[0];
    #pragma unroll
    for (int i = 1; i < WAVES_PER_BLOCK; ++i) {
      pm = fmaxf(pm, s_pos[i]);
      nm = fminf(nm, s_neg[i]);
    }
    ws[1 + blockIdx.x] = pm;
    ws[1 + NBLOCKS + blockIdx.x] = nm;
  }
}

// Stage 2: one block reduces the NBLOCKS partials and writes the scalar loss.
__global__ __launch_bounds__(BLOCK) void triplet_stage2(
    const float* __restrict__ ws,
    float* __restrict__ out) {
  __shared__ float s_pos[WAVES_PER_BLOCK];
  __shared__ float s_neg[WAVES_PER_BLOCK];

  const int lane = threadIdx.x & 63;
  const int wid  = threadIdx.x >> 6;

  float pm = -INFINITY;
  float nm =  INFINITY;
  for (int i = threadIdx.x; i < NBLOCKS; i += BLOCK) {
    pm = fmaxf(pm, ws[1 + i]);
    nm = fminf(nm, ws[1 + NBLOCKS + i]);
  }
  #pragma unroll
  for (int off = 32; off > 0; off >>= 1) {
    pm = fmaxf(pm, __shfl_xor(pm, off, 64));
    nm = fminf(nm, __shfl_xor(nm, off, 64));
  }
  if (lane == 0) {
    s_pos[wid] = pm;
    s_neg[wid] = nm;
  }
  __syncthreads();
  if (threadIdx.x == 0) {
    float fpm = s_pos[0];
    float fnm = s_neg[0];
    #pragma unroll
    for (int i = 1; i < WAVES_PER_BLOCK; ++i) {
      fpm = fmaxf(fpm, s_pos[i]);
      fnm = fminf(fnm, s_neg[i]);
    }
    if (fpm == -INFINITY) fpm = ws[0];  // no positive under margin -> index 0
    out[0] = fmaxf(fpm - fnm + MARGIN, 0.0f);
  }
}

extern "C" void kernel_launch(void* const* d_in, const int* in_sizes, int n_in,
                              void* d_out, int out_size, void* d_ws, size_t ws_size,
                              hipStream_t stream) {
  const float* anchor = (const float*)d_in[0];
  const float* pos    = (const float*)d_in[1];
  const float* neg    = (const float*)d_in[2];
  float* out = (float*)d_out;
  float* ws  = (float*)d_ws;

  triplet_stage1<<<NBLOCKS, BLOCK, 0, stream>>>(anchor, pos, neg, ws);
  triplet_stage2<<<1, BLOCK, 0, stream>>>(ws, out);
}